// Round 1
// baseline (3148.163 us; speedup 1.0000x reference)
//
#include <hip/hip_runtime.h>
#include <math.h>

#define NN 100000
#define NE 1600000
#define DD 128
#define FE 32

// ---------------------------------------------------------------- x = h
__global__ __launch_bounds__(256) void k_copy(const float4* __restrict__ src,
                                              float4* __restrict__ dst, int n4) {
    int i = blockIdx.x * 256 + threadIdx.x;
    if (i < n4) dst[i] = src[i];
}

// ---------------------------------------------------------------- edges
// Per edge e: x[dst] += h[src] + edge_attr[e] @ W_e + b_e  (atomic)
// W_e column-slice (32 x float4) held in registers per lane; ea broadcast via LDS.
// Block 256 = 8 edges/iteration: lane slice c4=(t&31)*4 dims, e_local=t>>5.
__global__ __launch_bounds__(256) void k_edge(
    const float* __restrict__ h, const int* __restrict__ ei,
    const float* __restrict__ ea, const float* __restrict__ We,
    const float* __restrict__ be, float* x)
{
    __shared__ float eas[8 * 33];   // 8 edges x 32 feats, pad 33 to split banks
    __shared__ int   eis[16];
    const int t = threadIdx.x;
    const int e_local = t >> 5;
    const int c4 = (t & 31) * 4;

    float4 w[32];
#pragma unroll
    for (int k = 0; k < FE; ++k) w[k] = *(const float4*)(We + k * DD + c4);
    const float4 bv = *(const float4*)(be + c4);

    const int ngroups = NE / 8;   // 200000, exact
    for (int g = blockIdx.x; g < ngroups; g += gridDim.x) {
        __syncthreads();
        if (t < 16) eis[t] = ei[g * 16 + t];
        eas[(t >> 5) * 33 + (t & 31)] = ea[g * 256 + t];
        __syncthreads();
        const int esrc = eis[2 * e_local];
        const int edst = eis[2 * e_local + 1];
        float4 acc = bv;
#pragma unroll
        for (int k = 0; k < FE; ++k) {
            const float a = eas[e_local * 33 + k];
            acc.x += a * w[k].x; acc.y += a * w[k].y;
            acc.z += a * w[k].z; acc.w += a * w[k].w;
        }
        const float4 hv = *(const float4*)(h + esrc * DD + c4);
        acc.x += hv.x; acc.y += hv.y; acc.z += hv.z; acc.w += hv.w;
        float* xp = x + edst * DD + c4;
        atomicAdd(xp + 0, acc.x);
        atomicAdd(xp + 1, acc.y);
        atomicAdd(xp + 2, acc.z);
        atomicAdd(xp + 3, acc.w);
    }
}

// ---------------------------------------------------------------- node MLP
// xout = act(xin @ W + b); act = exact GELU or identity. In-place safe:
// each block reads its tile rows to LDS before writing them back.
// 128-row tile/block; wave owns 32 rows; lane: 8 rows x 8 cols register tile.
template<bool GELU>
__global__ __launch_bounds__(256) void k_mlp(
    const float* __restrict__ xin, const float* __restrict__ W,
    const float* __restrict__ b, float* xout)
{
    __shared__ float xs[128 * 132];   // pad 132: banks (4r+k)%32 distinct
    const int t = threadIdx.x;
    const int wave = t >> 6;
    const int lane = t & 63;
    const int rgrp = lane >> 4;           // 4 groups x 8 rows
    const int c8 = (lane & 15) * 8;       // 16 groups x 8 cols

    const float4 b0  = *(const float4*)(b + c8);
    const float4 b1v = *(const float4*)(b + c8 + 4);

    const int ntiles = (NN + 127) / 128;  // 782 (last tile partial)
    for (int tile = blockIdx.x; tile < ntiles; tile += gridDim.x) {
        const int row0 = tile * 128;
        __syncthreads();
#pragma unroll
        for (int j = 0; j < 16; ++j) {
            const int f4 = t + j * 256;       // 0..4095 float4s
            const int row = f4 >> 5;
            const int col = (f4 & 31) * 4;
            const int gr = row0 + row;
            float4 v = make_float4(0.f, 0.f, 0.f, 0.f);
            if (gr < NN) v = *(const float4*)(xin + gr * DD + col);
            *(float4*)(xs + row * 132 + col) = v;
        }
        __syncthreads();

        const int xbase = (wave * 32 + rgrp * 8) * 132;
        float acc[8][8];
#pragma unroll
        for (int i = 0; i < 8; ++i) {
            acc[i][0] = b0.x;  acc[i][1] = b0.y;  acc[i][2] = b0.z;  acc[i][3] = b0.w;
            acc[i][4] = b1v.x; acc[i][5] = b1v.y; acc[i][6] = b1v.z; acc[i][7] = b1v.w;
        }
#pragma unroll 2
        for (int k = 0; k < DD; ++k) {
            const float4 w0 = *(const float4*)(W + k * DD + c8);
            const float4 w1 = *(const float4*)(W + k * DD + c8 + 4);
#pragma unroll
            for (int i = 0; i < 8; ++i) {
                const float a = xs[xbase + i * 132 + k];
                acc[i][0] += a * w0.x; acc[i][1] += a * w0.y;
                acc[i][2] += a * w0.z; acc[i][3] += a * w0.w;
                acc[i][4] += a * w1.x; acc[i][5] += a * w1.y;
                acc[i][6] += a * w1.z; acc[i][7] += a * w1.w;
            }
        }

        const int rbase = row0 + wave * 32 + rgrp * 8;
#pragma unroll
        for (int i = 0; i < 8; ++i) {
            const int gr = rbase + i;
            if (gr < NN) {
                float o[8];
#pragma unroll
                for (int j = 0; j < 8; ++j) {
                    float v = acc[i][j];
                    if (GELU) v = 0.5f * v * (1.0f + erff(v * 0.70710678118654752f));
                    o[j] = v;
                }
                *(float4*)(xout + gr * DD + c8)     = make_float4(o[0], o[1], o[2], o[3]);
                *(float4*)(xout + gr * DD + c8 + 4) = make_float4(o[4], o[5], o[6], o[7]);
            }
        }
    }
}

// ----------------------------------------------------------------
extern "C" void kernel_launch(void* const* d_in, const int* in_sizes, int n_in,
                              void* d_out, int out_size, void* d_ws, size_t ws_size,
                              hipStream_t stream) {
    const float* h  = (const float*)d_in[0];
    const int*   ei = (const int*)d_in[1];
    const float* ea = (const float*)d_in[2];
    const float* We = (const float*)d_in[3];
    const float* be = (const float*)d_in[4];
    const float* W1 = (const float*)d_in[5];
    const float* b1 = (const float*)d_in[6];
    const float* W2 = (const float*)d_in[7];
    const float* b2 = (const float*)d_in[8];
    float* x = (float*)d_out;   // accumulator x = h + agg lives in d_out

    k_copy<<<(NN * DD / 4 + 255) / 256, 256, 0, stream>>>(
        (const float4*)h, (float4*)x, NN * DD / 4);
    k_edge<<<1536, 256, 0, stream>>>(h, ei, ea, We, be, x);
    k_mlp<true><<<1024, 256, 0, stream>>>(x, W1, b1, x);
    k_mlp<false><<<1024, 256, 0, stream>>>(x, W2, b2, x);
}

// Round 3
// 1065.833 us; speedup vs baseline: 2.9537x; 2.9537x over previous
//
#include <hip/hip_runtime.h>
#include <math.h>

#define NN 100000
#define NE 1600000
#define DD 128
#define FE 32

// ---- workspace layout (bytes) ----
#define OFF_COUNTS 0
#define OFF_STARTS 1600000
#define OFF_WCUR   3200000
#define OFF_CURSOR 4800000
#define OFF_ELIST  4800016
#define WS_NEEDED  (OFF_ELIST + NE * 4)

// ---------------------------------------------------------------- zero init
__global__ __launch_bounds__(256) void k_zero(int* __restrict__ counts,
                                              int* __restrict__ cursor) {
    int i = blockIdx.x * 256 + threadIdx.x;
    if (i < NN) counts[i] = 0;
    if (i == 0) cursor[0] = 0;
}

// ---------------------------------------------------------------- histogram
__global__ __launch_bounds__(256) void k_count(const int* __restrict__ ei,
                                               int* __restrict__ counts) {
    int e = blockIdx.x * 256 + threadIdx.x;
    if (e < NE) atomicAdd(&counts[ei[2 * e + 1]], 1);
}

// ---------------------------------------------------------------- slot alloc
// Per-wave inclusive scan of counts + one global-cursor atomic per wave.
__global__ __launch_bounds__(256) void k_alloc(const int* __restrict__ counts,
                                               int* __restrict__ starts,
                                               int* __restrict__ wcur,
                                               int* __restrict__ cursor) {
    int n = blockIdx.x * 256 + threadIdx.x;
    int lane = threadIdx.x & 63;
    int c = (n < NN) ? counts[n] : 0;
    int v = c;
#pragma unroll
    for (int d = 1; d < 64; d <<= 1) {
        int u = __shfl_up(v, d, 64);
        if (lane >= d) v += u;
    }
    int total = __shfl(v, 63, 64);
    int base = 0;
    if (lane == 63) base = atomicAdd(cursor, total);
    base = __shfl(base, 63, 64);
    int st = base + v - c;
    if (n < NN) { starts[n] = st; wcur[n] = st; }
}

// ---------------------------------------------------------------- CSR fill
__global__ __launch_bounds__(256) void k_fill(const int* __restrict__ ei,
                                              int* __restrict__ wcur,
                                              int* __restrict__ elist) {
    int e = blockIdx.x * 256 + threadIdx.x;
    if (e < NE) {
        int pos = atomicAdd(&wcur[ei[2 * e + 1]], 1);
        elist[pos] = e;
    }
}

// ---------------------------------------------------------------- aggregate
// One wave per node: x[n] = h[n] + deg*b_e + sum_e (h[src_e] + ea_e @ W_e).
// Lane owns 2 dims; W_e column-slice (32 x float2) in registers. Edge id and
// src are wave-uniform so ea-row reads scalarize/broadcast.
__global__ __launch_bounds__(256) void k_agg(
    const float* __restrict__ h, const int* __restrict__ ei,
    const float* __restrict__ ea, const float* __restrict__ We,
    const float* __restrict__ be, const int* __restrict__ starts,
    const int* __restrict__ counts, const int* __restrict__ elist,
    float* __restrict__ x)
{
    const int wave = threadIdx.x >> 6;
    const int lane = threadIdx.x & 63;
    const int n = blockIdx.x * 4 + wave;
    if (n >= NN) return;
    const int c2 = lane * 2;

    float2 w[FE];
#pragma unroll
    for (int k = 0; k < FE; ++k) w[k] = *(const float2*)(We + k * DD + c2);
    const float2 bv = *(const float2*)(be + c2);

    const int start = starts[n];
    const int deg = counts[n];

    float2 acc = *(const float2*)(h + (long long)n * DD + c2);
    const float fdeg = (float)deg;
    acc.x += fdeg * bv.x;
    acc.y += fdeg * bv.y;

    for (int j = 0; j < deg; ++j) {
        int e = elist[start + j];
        e = __builtin_amdgcn_readfirstlane(e);
        int src = ei[2 * e];
        src = __builtin_amdgcn_readfirstlane(src);
        const float* ar = ea + (long long)e * FE;
        const float2 hv = *(const float2*)(h + (long long)src * DD + c2);
        acc.x += hv.x;
        acc.y += hv.y;
#pragma unroll
        for (int k = 0; k < FE; ++k) {
            const float a = ar[k];
            acc.x += a * w[k].x;
            acc.y += a * w[k].y;
        }
    }
    *(float2*)(x + (long long)n * DD + c2) = acc;
}

// ---------------------------------------------------------------- fallback (atomic) path
__global__ __launch_bounds__(256) void k_copy(const float4* __restrict__ src,
                                              float4* __restrict__ dst, int n4) {
    int i = blockIdx.x * 256 + threadIdx.x;
    if (i < n4) dst[i] = src[i];
}

__global__ __launch_bounds__(256) void k_edge_atomic(
    const float* __restrict__ h, const int* __restrict__ ei,
    const float* __restrict__ ea, const float* __restrict__ We,
    const float* __restrict__ be, float* x)
{
    __shared__ float eas[8 * 33];
    __shared__ int   eis[16];
    const int t = threadIdx.x;
    const int e_local = t >> 5;
    const int c4 = (t & 31) * 4;

    float4 w[32];
#pragma unroll
    for (int k = 0; k < FE; ++k) w[k] = *(const float4*)(We + k * DD + c4);
    const float4 bv = *(const float4*)(be + c4);

    const int ngroups = NE / 8;
    for (int g = blockIdx.x; g < ngroups; g += gridDim.x) {
        __syncthreads();
        if (t < 16) eis[t] = ei[g * 16 + t];
        eas[(t >> 5) * 33 + (t & 31)] = ea[g * 256 + t];
        __syncthreads();
        const int esrc = eis[2 * e_local];
        const int edst = eis[2 * e_local + 1];
        float4 acc = bv;
#pragma unroll
        for (int k = 0; k < FE; ++k) {
            const float a = eas[e_local * 33 + k];
            acc.x += a * w[k].x; acc.y += a * w[k].y;
            acc.z += a * w[k].z; acc.w += a * w[k].w;
        }
        const float4 hv = *(const float4*)(h + esrc * DD + c4);
        acc.x += hv.x; acc.y += hv.y; acc.z += hv.z; acc.w += hv.w;
        float* xp = x + edst * DD + c4;
        atomicAdd(xp + 0, acc.x);
        atomicAdd(xp + 1, acc.y);
        atomicAdd(xp + 2, acc.z);
        atomicAdd(xp + 3, acc.w);
    }
}

// ---------------------------------------------------------------- node MLP
template<bool GELU>
__global__ __launch_bounds__(256) void k_mlp(
    const float* __restrict__ xin, const float* __restrict__ W,
    const float* __restrict__ b, float* xout)
{
    __shared__ float xs[128 * 132];
    const int t = threadIdx.x;
    const int wave = t >> 6;
    const int lane = t & 63;
    const int rgrp = lane >> 4;
    const int c8 = (lane & 15) * 8;

    const float4 b0  = *(const float4*)(b + c8);
    const float4 b1v = *(const float4*)(b + c8 + 4);

    const int ntiles = (NN + 127) / 128;
    for (int tile = blockIdx.x; tile < ntiles; tile += gridDim.x) {
        const int row0 = tile * 128;
        __syncthreads();
#pragma unroll
        for (int j = 0; j < 16; ++j) {
            const int f4 = t + j * 256;
            const int row = f4 >> 5;
            const int col = (f4 & 31) * 4;
            const int gr = row0 + row;
            float4 v = make_float4(0.f, 0.f, 0.f, 0.f);
            if (gr < NN) v = *(const float4*)(xin + gr * DD + col);
            *(float4*)(xs + row * 132 + col) = v;
        }
        __syncthreads();

        const int xbase = (wave * 32 + rgrp * 8) * 132;
        float acc[8][8];
#pragma unroll
        for (int i = 0; i < 8; ++i) {
            acc[i][0] = b0.x;  acc[i][1] = b0.y;  acc[i][2] = b0.z;  acc[i][3] = b0.w;
            acc[i][4] = b1v.x; acc[i][5] = b1v.y; acc[i][6] = b1v.z; acc[i][7] = b1v.w;
        }
#pragma unroll 2
        for (int k = 0; k < DD; ++k) {
            const float4 w0 = *(const float4*)(W + k * DD + c8);
            const float4 w1 = *(const float4*)(W + k * DD + c8 + 4);
#pragma unroll
            for (int i = 0; i < 8; ++i) {
                const float a = xs[xbase + i * 132 + k];
                acc[i][0] += a * w0.x; acc[i][1] += a * w0.y;
                acc[i][2] += a * w0.z; acc[i][3] += a * w0.w;
                acc[i][4] += a * w1.x; acc[i][5] += a * w1.y;
                acc[i][6] += a * w1.z; acc[i][7] += a * w1.w;
            }
        }

        const int rbase = row0 + wave * 32 + rgrp * 8;
#pragma unroll
        for (int i = 0; i < 8; ++i) {
            const int gr = rbase + i;
            if (gr < NN) {
                float o[8];
#pragma unroll
                for (int j = 0; j < 8; ++j) {
                    float v = acc[i][j];
                    if (GELU) v = 0.5f * v * (1.0f + erff(v * 0.70710678118654752f));
                    o[j] = v;
                }
                *(float4*)(xout + gr * DD + c8)     = make_float4(o[0], o[1], o[2], o[3]);
                *(float4*)(xout + gr * DD + c8 + 4) = make_float4(o[4], o[5], o[6], o[7]);
            }
        }
    }
}

// ----------------------------------------------------------------
extern "C" void kernel_launch(void* const* d_in, const int* in_sizes, int n_in,
                              void* d_out, int out_size, void* d_ws, size_t ws_size,
                              hipStream_t stream) {
    const float* h  = (const float*)d_in[0];
    const int*   ei = (const int*)d_in[1];
    const float* ea = (const float*)d_in[2];
    const float* We = (const float*)d_in[3];
    const float* be = (const float*)d_in[4];
    const float* W1 = (const float*)d_in[5];
    const float* b1 = (const float*)d_in[6];
    const float* W2 = (const float*)d_in[7];
    const float* b2 = (const float*)d_in[8];
    float* x = (float*)d_out;

    if (ws_size >= (size_t)WS_NEEDED) {
        char* ws = (char*)d_ws;
        int* counts = (int*)(ws + OFF_COUNTS);
        int* starts = (int*)(ws + OFF_STARTS);
        int* wcur   = (int*)(ws + OFF_WCUR);
        int* cursor = (int*)(ws + OFF_CURSOR);
        int* elist  = (int*)(ws + OFF_ELIST);

        k_zero <<<(NN + 255) / 256, 256, 0, stream>>>(counts, cursor);
        k_count<<<(NE + 255) / 256, 256, 0, stream>>>(ei, counts);
        k_alloc<<<(NN + 255) / 256, 256, 0, stream>>>(counts, starts, wcur, cursor);
        k_fill <<<(NE + 255) / 256, 256, 0, stream>>>(ei, wcur, elist);
        k_agg  <<<(NN + 3) / 4, 256, 0, stream>>>(h, ei, ea, We, be,
                                                  starts, counts, elist, x);
    } else {
        // ws too small for CSR — atomic fallback (correct, slower)
        k_copy<<<(NN * DD / 4 + 255) / 256, 256, 0, stream>>>(
            (const float4*)h, (float4*)x, NN * DD / 4);
        k_edge_atomic<<<1536, 256, 0, stream>>>(h, ei, ea, We, be, x);
    }

    k_mlp<true> <<<1024, 256, 0, stream>>>(x, W1, b1, x);
    k_mlp<false><<<1024, 256, 0, stream>>>(x, W2, b2, x);
}

// Round 4
// 816.467 us; speedup vs baseline: 3.8558x; 1.3054x over previous
//
#include <hip/hip_runtime.h>
#include <math.h>

#define NN 100000
#define NE 1600000
#define DD 128
#define FE 32

typedef unsigned int uint;
typedef unsigned short ushort;
typedef __attribute__((ext_vector_type(8))) short short8;
typedef __attribute__((ext_vector_type(4))) float f32x4;

// ================= FULL-PATH workspace layout (bytes) =================
// counts int[NN] | starts int[NN] | wcur int[NN] | cursor | el2 int2[NE+NN]
// hbf bf16[NN*DD] (reused as y_bf16 by MLP1) | Wt1 | Wt2
#define F_COUNTS 0
#define F_STARTS 400000
#define F_WCUR   800000
#define F_CURSOR 1200000
#define F_EL2    1200016
#define F_HBF    14800128
#define F_WT1    40400128
#define F_WT2    40432896
#define WS_FULL  40465664

// ================= R3 (middle-tier) workspace layout =================
#define OFF_COUNTS 0
#define OFF_STARTS 1600000
#define OFF_WCUR   3200000
#define OFF_CURSOR 4800000
#define OFF_ELIST  4800016
#define WS_CSR     (OFF_ELIST + NE * 4)

// ---------------- helpers ----------------
__device__ __forceinline__ ushort f2bf(float v) {
    uint u = __float_as_uint(v);
    u += 0x7fffu + ((u >> 16) & 1u);
    return (ushort)(u >> 16);
}
__device__ __forceinline__ uint pack2bf(float x, float y) {
    return (uint)f2bf(x) | ((uint)f2bf(y) << 16);
}
__device__ __forceinline__ float2 unpack2bf(uint u) {
    float2 r;
    r.x = __uint_as_float(u << 16);
    r.y = __uint_as_float(u & 0xffff0000u);
    return r;
}

// ---------------------------------------------------------------- zero init
__global__ __launch_bounds__(256) void k_zero(int* __restrict__ counts,
                                              int* __restrict__ cursor) {
    int i = blockIdx.x * 256 + threadIdx.x;
    if (i < NN) counts[i] = 0;
    if (i == 0) cursor[0] = 0;
}

// ---------------------------------------------------------------- histogram
__global__ __launch_bounds__(256) void k_count(const int* __restrict__ ei,
                                               int* __restrict__ counts) {
    int e = blockIdx.x * 256 + threadIdx.x;
    if (e < NE) atomicAdd(&counts[ei[2 * e + 1]], 1);
}

// ---------------------------------------------------------------- slot alloc (pad starts to even)
__global__ __launch_bounds__(256) void k_alloc2(const int* __restrict__ counts,
                                                int* __restrict__ starts,
                                                int* __restrict__ wcur,
                                                int* __restrict__ cursor) {
    int n = blockIdx.x * 256 + threadIdx.x;
    int lane = threadIdx.x & 63;
    int c = (n < NN) ? counts[n] : 0;
    int cp = (c + 1) & ~1;          // pad to even so int4 loads stay aligned
    int v = cp;
#pragma unroll
    for (int d = 1; d < 64; d <<= 1) {
        int u = __shfl_up(v, d, 64);
        if (lane >= d) v += u;
    }
    int total = __shfl(v, 63, 64);
    int base = 0;
    if (lane == 63) base = atomicAdd(cursor, total);
    base = __shfl(base, 63, 64);
    int st = base + v - cp;
    if (n < NN) { starts[n] = st; wcur[n] = st; }
}

// ---------------------------------------------------------------- CSR fill: (e, src)
__global__ __launch_bounds__(256) void k_fill2(const int* __restrict__ ei,
                                               int* __restrict__ wcur,
                                               int2* __restrict__ el2) {
    int e = blockIdx.x * 256 + threadIdx.x;
    if (e < NE) {
        int2 d = *(const int2*)(ei + 2 * e);   // x=src, y=dst
        int pos = atomicAdd(&wcur[d.y], 1);
        el2[pos] = make_int2(e, d.x);
    }
}

// ---------------------------------------------------------------- h -> bf16
__global__ __launch_bounds__(256) void k_hcvt(const float* __restrict__ h,
                                              uint* __restrict__ hbf) {
    int i = blockIdx.x * 256 + threadIdx.x;  // one uint = 2 bf16
    if (i < NN * (DD / 2)) {
        float2 v = *(const float2*)(h + 2 * i);
        hbf[i] = pack2bf(v.x, v.y);
    }
}

// ---------------------------------------------------------------- W -> bf16 transposed Wt[n][k]
__global__ __launch_bounds__(256) void k_wcvt(const float* __restrict__ W1,
                                              const float* __restrict__ W2,
                                              ushort* __restrict__ Wt1,
                                              ushort* __restrict__ Wt2) {
    int idx = blockIdx.x * 256 + threadIdx.x;   // 0..32767
    int m = idx >> 14;
    int r = idx & 16383;
    int n = r >> 7, k = r & 127;
    const float* W = m ? W2 : W1;
    ushort* Wt = m ? Wt2 : Wt1;
    Wt[r] = f2bf(W[k * DD + n]);
}

// ---------------------------------------------------------------- aggregate v2
// Wave per node. x[n] = h[n] + deg*b_e + Sum h_bf16[src] + (Sum ea_e) @ W_e.
// Unroll 8 edges: 8 independent h-gathers + 4 ea loads + 4 int4 el2 loads in flight.
// Lane owns dims (2*lane, 2*lane+1). ea accumulated per half-wave (feature lane&31).
// Output: x as packed bf16 (uint per lane) into xbf (front of d_out used as scratch).
__global__ __launch_bounds__(256) void k_agg2(
    const float* __restrict__ h, const uint* __restrict__ hbf,
    const float* __restrict__ ea, const float* __restrict__ We,
    const float* __restrict__ be, const int* __restrict__ starts,
    const int* __restrict__ counts, const int2* __restrict__ el2,
    uint* __restrict__ xbf)
{
    const int wave = threadIdx.x >> 6;
    const int lane = threadIdx.x & 63;
    const int n = blockIdx.x * 4 + wave;        // grid 25000 -> exact
    const int c2 = lane * 2;
    const int f = lane & 31;
    const bool hi = lane >= 32;

    float2 w[FE];
#pragma unroll
    for (int k = 0; k < FE; ++k) w[k] = *(const float2*)(We + k * DD + c2);
    const float2 bv = *(const float2*)(be + c2);

    const int s = starts[n];
    const int deg = counts[n];

    float2 hv = *(const float2*)(h + n * DD + c2);
    float2 acc = make_float2(hv.x + (float)deg * bv.x, hv.y + (float)deg * bv.y);
    float eacc = 0.f;

    int j = 0;
    for (; j + 8 <= deg; j += 8) {
        int4 q0 = *(const int4*)(el2 + s + j);
        int4 q1 = *(const int4*)(el2 + s + j + 2);
        int4 q2 = *(const int4*)(el2 + s + j + 4);
        int4 q3 = *(const int4*)(el2 + s + j + 6);
        uint g0 = hbf[q0.y * 64 + lane];
        uint g1 = hbf[q0.w * 64 + lane];
        uint g2 = hbf[q1.y * 64 + lane];
        uint g3 = hbf[q1.w * 64 + lane];
        uint g4 = hbf[q2.y * 64 + lane];
        uint g5 = hbf[q2.w * 64 + lane];
        uint g6 = hbf[q3.y * 64 + lane];
        uint g7 = hbf[q3.w * 64 + lane];
        float a0 = ea[(hi ? q0.z : q0.x) * FE + f];
        float a1 = ea[(hi ? q1.z : q1.x) * FE + f];
        float a2 = ea[(hi ? q2.z : q2.x) * FE + f];
        float a3 = ea[(hi ? q3.z : q3.x) * FE + f];
        eacc += (a0 + a1) + (a2 + a3);
        float2 t;
        t = unpack2bf(g0); acc.x += t.x; acc.y += t.y;
        t = unpack2bf(g1); acc.x += t.x; acc.y += t.y;
        t = unpack2bf(g2); acc.x += t.x; acc.y += t.y;
        t = unpack2bf(g3); acc.x += t.x; acc.y += t.y;
        t = unpack2bf(g4); acc.x += t.x; acc.y += t.y;
        t = unpack2bf(g5); acc.x += t.x; acc.y += t.y;
        t = unpack2bf(g6); acc.x += t.x; acc.y += t.y;
        t = unpack2bf(g7); acc.x += t.x; acc.y += t.y;
    }
    for (; j < deg; ++j) {
        int2 p = el2[s + j];
        uint g = hbf[p.y * 64 + lane];
        float a = 0.f;
        if (!hi) a = ea[p.x * FE + f];
        eacc += a;
        float2 t = unpack2bf(g);
        acc.x += t.x; acc.y += t.y;
    }
    // combine half-wave ea accumulators: all lanes hold total for feature lane&31
    eacc += __shfl(eacc, lane ^ 32, 64);
    // (Sum ea) @ W_e for this lane's two columns
#pragma unroll
    for (int k = 0; k < FE; ++k) {
        float a = __shfl(eacc, k, 64);
        acc.x += a * w[k].x;
        acc.y += a * w[k].y;
    }
    xbf[n * 64 + lane] = pack2bf(acc.x, acc.y);
}

// ---------------------------------------------------------------- MFMA MLP
// out = act(x @ W + b). x: bf16 [NN,128]; Wt: bf16 transposed [n][k]; out: bf16 or fp32.
// Wave handles a 16-row tile, full 128 cols: 8 col-tiles x 4 k-chunks of MFMA 16x16x32.
// Wt staged in LDS with +8 ushort row pad (conflict-free b128 frag reads).
template<bool GELU, bool OUTBF>
__global__ __launch_bounds__(256) void k_mlp_mfma(
    const ushort* __restrict__ xin, const ushort* __restrict__ Wt,
    const float* __restrict__ b, void* __restrict__ out)
{
    __shared__ ushort wlds[128 * 136];
    const int t = threadIdx.x;
    const int wave = t >> 6;
    const int lane = t & 63;
    const int l16 = lane & 15;
    const int quad = lane >> 4;

    // stage Wt: 2048 slots of 8 ushorts
#pragma unroll
    for (int i = 0; i < 8; ++i) {
        int slot = t + i * 256;
        int nrow = slot >> 4;
        int koff = (slot & 15) * 8;
        *(short8*)(wlds + nrow * 136 + koff) = *(const short8*)(Wt + nrow * 128 + koff);
    }
    __syncthreads();

    float bias[8];
#pragma unroll
    for (int c = 0; c < 8; ++c) bias[c] = b[c * 16 + l16];

    const int ntiles = NN / 16;   // 6250 exact
    for (int tile = blockIdx.x * 4 + wave; tile < ntiles; tile += gridDim.x * 4) {
        const int row = tile * 16 + l16;
        short8 a[4];
#pragma unroll
        for (int q = 0; q < 4; ++q)
            a[q] = *(const short8*)(xin + row * DD + q * 32 + quad * 8);

        f32x4 acc[8];
#pragma unroll
        for (int c = 0; c < 8; ++c) acc[c] = (f32x4){0.f, 0.f, 0.f, 0.f};

#pragma unroll
        for (int c = 0; c < 8; ++c) {
            const int nb = (c * 16 + l16) * 136 + quad * 8;
#pragma unroll
            for (int q = 0; q < 4; ++q) {
                short8 bf = *(const short8*)(wlds + nb + q * 32);
                acc[c] = __builtin_amdgcn_mfma_f32_16x16x32_bf16(a[q], bf, acc[c], 0, 0, 0);
            }
        }

        const int r0 = tile * 16 + quad * 4;
#pragma unroll
        for (int c = 0; c < 8; ++c) {
            const int col = c * 16 + l16;
#pragma unroll
            for (int r = 0; r < 4; ++r) {
                float v = acc[c][r] + bias[c];
                if (GELU) v = 0.5f * v * (1.0f + erff(v * 0.70710678118654752f));
                if (OUTBF) ((ushort*)out)[(r0 + r) * DD + col] = f2bf(v);
                else       ((float*)out)[(r0 + r) * DD + col] = v;
            }
        }
    }
}

// ================================================================ middle tier (R3, proven)
__global__ __launch_bounds__(256) void k_alloc(const int* __restrict__ counts,
                                               int* __restrict__ starts,
                                               int* __restrict__ wcur,
                                               int* __restrict__ cursor) {
    int n = blockIdx.x * 256 + threadIdx.x;
    int lane = threadIdx.x & 63;
    int c = (n < NN) ? counts[n] : 0;
    int v = c;
#pragma unroll
    for (int d = 1; d < 64; d <<= 1) {
        int u = __shfl_up(v, d, 64);
        if (lane >= d) v += u;
    }
    int total = __shfl(v, 63, 64);
    int base = 0;
    if (lane == 63) base = atomicAdd(cursor, total);
    base = __shfl(base, 63, 64);
    int st = base + v - c;
    if (n < NN) { starts[n] = st; wcur[n] = st; }
}

__global__ __launch_bounds__(256) void k_fill(const int* __restrict__ ei,
                                              int* __restrict__ wcur,
                                              int* __restrict__ elist) {
    int e = blockIdx.x * 256 + threadIdx.x;
    if (e < NE) {
        int pos = atomicAdd(&wcur[ei[2 * e + 1]], 1);
        elist[pos] = e;
    }
}

__global__ __launch_bounds__(256) void k_agg(
    const float* __restrict__ h, const int* __restrict__ ei,
    const float* __restrict__ ea, const float* __restrict__ We,
    const float* __restrict__ be, const int* __restrict__ starts,
    const int* __restrict__ counts, const int* __restrict__ elist,
    float* __restrict__ x)
{
    const int wave = threadIdx.x >> 6;
    const int lane = threadIdx.x & 63;
    const int n = blockIdx.x * 4 + wave;
    if (n >= NN) return;
    const int c2 = lane * 2;
    float2 w[FE];
#pragma unroll
    for (int k = 0; k < FE; ++k) w[k] = *(const float2*)(We + k * DD + c2);
    const float2 bv = *(const float2*)(be + c2);
    const int start = starts[n];
    const int deg = counts[n];
    float2 acc = *(const float2*)(h + (long long)n * DD + c2);
    const float fdeg = (float)deg;
    acc.x += fdeg * bv.x;
    acc.y += fdeg * bv.y;
    for (int j = 0; j < deg; ++j) {
        int e = elist[start + j];
        e = __builtin_amdgcn_readfirstlane(e);
        int src = ei[2 * e];
        src = __builtin_amdgcn_readfirstlane(src);
        const float* ar = ea + (long long)e * FE;
        const float2 hv = *(const float2*)(h + (long long)src * DD + c2);
        acc.x += hv.x;
        acc.y += hv.y;
#pragma unroll
        for (int k = 0; k < FE; ++k) {
            const float a = ar[k];
            acc.x += a * w[k].x;
            acc.y += a * w[k].y;
        }
    }
    *(float2*)(x + (long long)n * DD + c2) = acc;
}

__global__ __launch_bounds__(256) void k_copy(const float4* __restrict__ src,
                                              float4* __restrict__ dst, int n4) {
    int i = blockIdx.x * 256 + threadIdx.x;
    if (i < n4) dst[i] = src[i];
}

__global__ __launch_bounds__(256) void k_edge_atomic(
    const float* __restrict__ h, const int* __restrict__ ei,
    const float* __restrict__ ea, const float* __restrict__ We,
    const float* __restrict__ be, float* x)
{
    __shared__ float eas[8 * 33];
    __shared__ int   eis[16];
    const int t = threadIdx.x;
    const int e_local = t >> 5;
    const int c4 = (t & 31) * 4;
    float4 w[32];
#pragma unroll
    for (int k = 0; k < FE; ++k) w[k] = *(const float4*)(We + k * DD + c4);
    const float4 bv = *(const float4*)(be + c4);
    const int ngroups = NE / 8;
    for (int g = blockIdx.x; g < ngroups; g += gridDim.x) {
        __syncthreads();
        if (t < 16) eis[t] = ei[g * 16 + t];
        eas[(t >> 5) * 33 + (t & 31)] = ea[g * 256 + t];
        __syncthreads();
        const int esrc = eis[2 * e_local];
        const int edst = eis[2 * e_local + 1];
        float4 acc = bv;
#pragma unroll
        for (int k = 0; k < FE; ++k) {
            const float a = eas[e_local * 33 + k];
            acc.x += a * w[k].x; acc.y += a * w[k].y;
            acc.z += a * w[k].z; acc.w += a * w[k].w;
        }
        const float4 hv = *(const float4*)(h + esrc * DD + c4);
        acc.x += hv.x; acc.y += hv.y; acc.z += hv.z; acc.w += hv.w;
        float* xp = x + edst * DD + c4;
        atomicAdd(xp + 0, acc.x);
        atomicAdd(xp + 1, acc.y);
        atomicAdd(xp + 2, acc.z);
        atomicAdd(xp + 3, acc.w);
    }
}

template<bool GELU>
__global__ __launch_bounds__(256) void k_mlp(
    const float* __restrict__ xin, const float* __restrict__ W,
    const float* __restrict__ b, float* xout)
{
    __shared__ float xs[128 * 132];
    const int t = threadIdx.x;
    const int wave = t >> 6;
    const int lane = t & 63;
    const int rgrp = lane >> 4;
    const int c8 = (lane & 15) * 8;
    const float4 b0  = *(const float4*)(b + c8);
    const float4 b1v = *(const float4*)(b + c8 + 4);
    const int ntiles = (NN + 127) / 128;
    for (int tile = blockIdx.x; tile < ntiles; tile += gridDim.x) {
        const int row0 = tile * 128;
        __syncthreads();
#pragma unroll
        for (int j = 0; j < 16; ++j) {
            const int f4 = t + j * 256;
            const int row = f4 >> 5;
            const int col = (f4 & 31) * 4;
            const int gr = row0 + row;
            float4 v = make_float4(0.f, 0.f, 0.f, 0.f);
            if (gr < NN) v = *(const float4*)(xin + gr * DD + col);
            *(float4*)(xs + row * 132 + col) = v;
        }
        __syncthreads();
        const int xbase = (wave * 32 + rgrp * 8) * 132;
        float acc[8][8];
#pragma unroll
        for (int i = 0; i < 8; ++i) {
            acc[i][0] = b0.x;  acc[i][1] = b0.y;  acc[i][2] = b0.z;  acc[i][3] = b0.w;
            acc[i][4] = b1v.x; acc[i][5] = b1v.y; acc[i][6] = b1v.z; acc[i][7] = b1v.w;
        }
#pragma unroll 2
        for (int k = 0; k < DD; ++k) {
            const float4 w0 = *(const float4*)(W + k * DD + c8);
            const float4 w1 = *(const float4*)(W + k * DD + c8 + 4);
#pragma unroll
            for (int i = 0; i < 8; ++i) {
                const float a = xs[xbase + i * 132 + k];
                acc[i][0] += a * w0.x; acc[i][1] += a * w0.y;
                acc[i][2] += a * w0.z; acc[i][3] += a * w0.w;
                acc[i][4] += a * w1.x; acc[i][5] += a * w1.y;
                acc[i][6] += a * w1.z; acc[i][7] += a * w1.w;
            }
        }
        const int rbase = row0 + wave * 32 + rgrp * 8;
#pragma unroll
        for (int i = 0; i < 8; ++i) {
            const int gr = rbase + i;
            if (gr < NN) {
                float o[8];
#pragma unroll
                for (int j = 0; j < 8; ++j) {
                    float v = acc[i][j];
                    if (GELU) v = 0.5f * v * (1.0f + erff(v * 0.70710678118654752f));
                    o[j] = v;
                }
                *(float4*)(xout + gr * DD + c8)     = make_float4(o[0], o[1], o[2], o[3]);
                *(float4*)(xout + gr * DD + c8 + 4) = make_float4(o[4], o[5], o[6], o[7]);
            }
        }
    }
}

// ----------------------------------------------------------------
extern "C" void kernel_launch(void* const* d_in, const int* in_sizes, int n_in,
                              void* d_out, int out_size, void* d_ws, size_t ws_size,
                              hipStream_t stream) {
    const float* h  = (const float*)d_in[0];
    const int*   ei = (const int*)d_in[1];
    const float* ea = (const float*)d_in[2];
    const float* We = (const float*)d_in[3];
    const float* be = (const float*)d_in[4];
    const float* W1 = (const float*)d_in[5];
    const float* b1 = (const float*)d_in[6];
    const float* W2 = (const float*)d_in[7];
    const float* b2 = (const float*)d_in[8];
    float* x = (float*)d_out;
    char* ws = (char*)d_ws;

    if (ws_size >= (size_t)WS_FULL) {
        int*    counts = (int*)(ws + F_COUNTS);
        int*    starts = (int*)(ws + F_STARTS);
        int*    wcur   = (int*)(ws + F_WCUR);
        int*    cursor = (int*)(ws + F_CURSOR);
        int2*   el2    = (int2*)(ws + F_EL2);
        uint*   hbf    = (uint*)(ws + F_HBF);       // h bf16; later reused as y bf16
        ushort* Wt1    = (ushort*)(ws + F_WT1);
        ushort* Wt2    = (ushort*)(ws + F_WT2);
        uint*   xbf    = (uint*)d_out;              // x bf16 scratch in d_out front

        k_zero  <<<(NN + 255) / 256, 256, 0, stream>>>(counts, cursor);
        k_count <<<(NE + 255) / 256, 256, 0, stream>>>(ei, counts);
        k_alloc2<<<(NN + 255) / 256, 256, 0, stream>>>(counts, starts, wcur, cursor);
        k_fill2 <<<(NE + 255) / 256, 256, 0, stream>>>(ei, wcur, el2);
        k_hcvt  <<<(NN * (DD / 2) + 255) / 256, 256, 0, stream>>>(h, hbf);
        k_wcvt  <<<128, 256, 0, stream>>>(W1, W2, Wt1, Wt2);
        k_agg2  <<<NN / 4, 256, 0, stream>>>(h, hbf, ea, We, be,
                                             starts, counts, el2, xbf);
        // MLP1: x(bf16, d_out) -> y(bf16, hbf region); MLP2: y -> d_out fp32
        k_mlp_mfma<true,  true ><<<1563, 256, 0, stream>>>((const ushort*)xbf, Wt1, b1, (void*)hbf);
        k_mlp_mfma<false, false><<<1563, 256, 0, stream>>>((const ushort*)hbf, Wt2, b2, (void*)d_out);
    } else if (ws_size >= (size_t)WS_CSR) {
        int* counts = (int*)(ws + OFF_COUNTS);
        int* starts = (int*)(ws + OFF_STARTS);
        int* wcur   = (int*)(ws + OFF_WCUR);
        int* cursor = (int*)(ws + OFF_CURSOR);
        int* elist  = (int*)(ws + OFF_ELIST);
        k_zero <<<(NN + 255) / 256, 256, 0, stream>>>(counts, cursor);
        k_count<<<(NE + 255) / 256, 256, 0, stream>>>(ei, counts);
        k_alloc<<<(NN + 255) / 256, 256, 0, stream>>>(counts, starts, wcur, cursor);
        k_fill <<<(NE + 255) / 256, 256, 0, stream>>>(ei, wcur, elist);
        k_agg  <<<(NN + 3) / 4, 256, 0, stream>>>(h, ei, ea, We, be,
                                                  starts, counts, elist, x);
        k_mlp<true> <<<1024, 256, 0, stream>>>(x, W1, b1, x);
        k_mlp<false><<<1024, 256, 0, stream>>>(x, W2, b2, x);
    } else {
        k_copy<<<(NN * DD / 4 + 255) / 256, 256, 0, stream>>>(
            (const float4*)h, (float4*)x, NN * DD / 4);
        k_edge_atomic<<<1536, 256, 0, stream>>>(h, ei, ea, We, be, x);
        k_mlp<true> <<<1024, 256, 0, stream>>>(x, W1, b1, x);
        k_mlp<false><<<1024, 256, 0, stream>>>(x, W2, b2, x);
    }
}